// Round 3
// baseline (304.464 us; speedup 1.0000x reference)
//
#include <hip/hip_runtime.h>
#include <cmath>

typedef __attribute__((ext_vector_type(8))) short short8;
typedef __attribute__((ext_vector_type(4))) float floatx4;

#define T_TOK 32768
#define DIMK 512

__device__ __forceinline__ unsigned short f2bf(float f) {
  union { float f; unsigned int u; } v; v.f = f;
  unsigned int r = (v.u + 0x7fffu + ((v.u >> 16) & 1u)) >> 16;
  return (unsigned short)r;
}
__device__ __forceinline__ float bf2f(unsigned short h) {
  union { unsigned int u; float f; } v; v.u = ((unsigned int)h) << 16;
  return v.f;
}

// async global->LDS 16B per lane: HW writes lane i at ldsbase + i*16
__device__ __forceinline__ void gload_lds16(const unsigned short* g, unsigned short* ldsbase) {
  __builtin_amdgcn_global_load_lds(
      (const __attribute__((address_space(1))) unsigned int*)g,
      (__attribute__((address_space(3))) unsigned int*)ldsbase, 16, 0, 0);
}

// ------- setup: weight bf16 convert + rope table + KV/Ksum zero (one launch) -------
__global__ __launch_bounds__(256) void k_setup(const float* __restrict__ wq,
    const float* __restrict__ wk, const float* __restrict__ wv,
    const float* __restrict__ wo, unsigned short* __restrict__ Wb,
    unsigned short* __restrict__ wob, float2* __restrict__ rope,
    float* __restrict__ KVz) {
  int i = blockIdx.x * 256 + threadIdx.x;  // 524288
  float v;
  if (i < 262144) v = wq[i];
  else if (i < 393216) v = wk[i - 262144];
  else v = wv[i - 393216];
  Wb[i] = f2bf(v);
  if (i < 262144) {
    wob[i] = f2bf(wo[i]);
    // rope: inv[m] = 10^(-m/8) exact double mul chain; range-reduce mod 2pi in f64
    int s = i >> 5, m = i & 31;
    const double c0 = 0.74989420933245582;   // 10^(-1/8)
    double c1 = c0 * c0, c2 = c1 * c1, c3 = c2 * c2, c4 = c3 * c3;
    double p = 1.0;
    if (m & 1)  p *= c0;
    if (m & 2)  p *= c1;
    if (m & 4)  p *= c2;
    if (m & 8)  p *= c3;
    if (m & 16) p *= c4;
    double ang = (double)s * p;
    const double TWO_PI = 6.2831853071795864769;
    double q = rint(ang * (1.0 / TWO_PI));
    double r = fma(-q, TWO_PI, ang);
    float rf = (float)r;
    rope[i] = make_float2(cosf(rf), sinf(rf));
  }
  if (i < 2048) KVz[i] = 0.f;
}

// ------- RMSNorm: one wave per token, float4 loads, no LDS -------
__global__ __launch_bounds__(256) void k_rmsnorm(const float* __restrict__ x,
    const float* __restrict__ w, unsigned short* __restrict__ xn) {
  int wave = threadIdx.x >> 6, lane = threadIdx.x & 63;
  size_t t = (size_t)blockIdx.x * 4 + wave;
  const float4* xr = (const float4*)(x + t * DIMK);
  float4 a = xr[lane * 2];
  float4 b = xr[lane * 2 + 1];
  float ss = a.x * a.x + a.y * a.y + a.z * a.z + a.w * a.w
           + b.x * b.x + b.y * b.y + b.z * b.z + b.w * b.w;
  #pragma unroll
  for (int off = 32; off >= 1; off >>= 1) ss += __shfl_xor(ss, off, 64);
  float scale = rsqrtf(ss * (1.0f / DIMK) + 1e-6f);
  const float4* wr = (const float4*)w;
  float4 w0 = wr[lane * 2], w1 = wr[lane * 2 + 1];
  uint4 o;
  o.x = (unsigned int)f2bf(a.x * scale * w0.x) | ((unsigned int)f2bf(a.y * scale * w0.y) << 16);
  o.y = (unsigned int)f2bf(a.z * scale * w0.z) | ((unsigned int)f2bf(a.w * scale * w0.w) << 16);
  o.z = (unsigned int)f2bf(b.x * scale * w1.x) | ((unsigned int)f2bf(b.y * scale * w1.y) << 16);
  o.w = (unsigned int)f2bf(b.z * scale * w1.z) | ((unsigned int)f2bf(b.w * scale * w1.w) << 16);
  *(uint4*)(xn + t * DIMK + lane * 8) = o;
}

// ------- GEMM1: qkv(M,1024) = xn(M,512) * Wb(1024,512)^T, bf16 out -------
// 128x128 tile; blockIdx.x = ROW tile (fast dim) so same-A blocks share an XCD.
__global__ __launch_bounds__(256) void k_gemm128(const unsigned short* __restrict__ A,
    const unsigned short* __restrict__ Bw, unsigned short* __restrict__ C, int N) {
  constexpr int K = DIMK;
  constexpr int BK = 64;
  __shared__ __align__(16) unsigned short As[128 * BK];
  __shared__ __align__(16) unsigned short Bs[128 * BK];
  const int tid = threadIdx.x;
  const int wave = tid >> 6, lane = tid & 63;
  const int r = lane & 15, quad = lane >> 4;
  const int wm = (wave >> 1) * 64, wn = (wave & 1) * 64;
  const int m0 = blockIdx.x * 128, n0 = blockIdx.y * 128;

  const int srow = (lane >> 3);
  const int scol = (lane & 7) * 8;
  const unsigned short* Ag[4];
  const unsigned short* Bg[4];
  unsigned short* Al[4];
  unsigned short* Bl[4];
  #pragma unroll
  for (int li = 0; li < 4; li++) {
    int row = wave * 32 + li * 8 + srow;
    Ag[li] = A  + (size_t)(m0 + row) * K + scol;
    Bg[li] = Bw + (size_t)(n0 + row) * K + scol;
    Al[li] = &As[(wave * 4 + li) * 512];
    Bl[li] = &Bs[(wave * 4 + li) * 512];
  }

  floatx4 acc[4][4];
  #pragma unroll
  for (int i = 0; i < 4; i++)
    #pragma unroll
    for (int j = 0; j < 4; j++)
      acc[i][j] = (floatx4){0.f, 0.f, 0.f, 0.f};

  for (int k0 = 0; k0 < K; k0 += BK) {
    #pragma unroll
    for (int li = 0; li < 4; li++) {
      gload_lds16(Ag[li] + k0, Al[li]);
      gload_lds16(Bg[li] + k0, Bl[li]);
    }
    __syncthreads();
    #pragma unroll
    for (int kk = 0; kk < BK; kk += 32) {
      short8 af[4], bfv[4];
      #pragma unroll
      for (int i = 0; i < 4; i++)
        af[i] = *(const short8*)&As[(wm + i * 16 + r) * BK + kk + quad * 8];
      #pragma unroll
      for (int j = 0; j < 4; j++)
        bfv[j] = *(const short8*)&Bs[(wn + j * 16 + r) * BK + kk + quad * 8];
      #pragma unroll
      for (int i = 0; i < 4; i++)
        #pragma unroll
        for (int j = 0; j < 4; j++)
          acc[i][j] = __builtin_amdgcn_mfma_f32_16x16x32_bf16(af[i], bfv[j], acc[i][j], 0, 0, 0);
    }
    __syncthreads();
  }
  #pragma unroll
  for (int i = 0; i < 4; i++)
    #pragma unroll
    for (int j = 0; j < 4; j++) {
      int row = m0 + wm + i * 16 + quad * 4;
      int col = n0 + wn + j * 16 + r;
      #pragma unroll
      for (int p = 0; p < 4; p++)
        C[(size_t)(row + p) * N + col] = f2bf(acc[i][j][p]);
    }
}

// ------- KV / Ksum reduction over sequence -------
__global__ __launch_bounds__(256) void k_kvred(const unsigned short* __restrict__ qkv,
    const float2* __restrict__ rope, float* __restrict__ KV, float* __restrict__ Ksum) {
  int bk = blockIdx.y;
  int b = bk >> 2, kh = bk & 3;
  int tid = threadIdx.x;
  int m = tid & 31;
  int sl = tid >> 5;
  int s0 = blockIdx.x * 256;
  float kvr = 0.f, kvi = 0.f, ksr = 0.f, ksi = 0.f;
  for (int si = sl; si < 256; si += 8) {
    int s = s0 + si;
    size_t t = (size_t)b * 8192 + s;
    const unsigned short* base = qkv + t * 1024;
    unsigned int kp = *(const unsigned int*)(base + 512 + kh * 64 + 2 * m);
    unsigned int vp = *(const unsigned int*)(base + 768 + kh * 64 + 2 * m);
    float kx = bf2f((unsigned short)(kp & 0xffffu));
    float ky = bf2f((unsigned short)(kp >> 16));
    float vx = bf2f((unsigned short)(vp & 0xffffu));
    float vy = bf2f((unsigned short)(vp >> 16));
    float2 cs = rope[s * 32 + m];
    float kr = kx * cs.x - ky * cs.y;
    float ki = kx * cs.y + ky * cs.x;
    kr = kr > 0.f ? kr + 1.f : __expf(kr);
    ki = ki > 0.f ? ki + 1.f : __expf(ki);
    kvr += kr * vx; kvi += ki * vy;
    ksr += kr;      ksi += ki;
  }
  __shared__ float red[256 * 4];
  red[tid * 4 + 0] = kvr; red[tid * 4 + 1] = kvi;
  red[tid * 4 + 2] = ksr; red[tid * 4 + 3] = ksi;
  __syncthreads();
  if (sl == 0) {
    for (int q = 1; q < 8; q++) {
      kvr += red[(q * 32 + m) * 4 + 0]; kvi += red[(q * 32 + m) * 4 + 1];
      ksr += red[(q * 32 + m) * 4 + 2]; ksi += red[(q * 32 + m) * 4 + 3];
    }
    atomicAdd(&KV[bk * 64 + 2 * m], kvr);
    atomicAdd(&KV[bk * 64 + 2 * m + 1], kvi);
    atomicAdd(&Ksum[bk * 64 + 2 * m], ksr);
    atomicAdd(&Ksum[bk * 64 + 2 * m + 1], ksi);
  }
}

// ------- fused output GEMM: out(M,512) = Y(M,512) * wob(512,512)^T -------
// Y computed on the fly per K-slice: slice k0=h*64 of Y depends only on q-head h
// (rope+phi per pair, Z = 64-dot with Ksum, scale by KV/(Z+eps)).
__global__ __launch_bounds__(256) void k_gemm_out(const unsigned short* __restrict__ qkv,
    const unsigned short* __restrict__ wob, const float2* __restrict__ rope,
    const float* __restrict__ KV, const float* __restrict__ Ksum,
    float* __restrict__ C) {
  constexpr int N = 512;
  __shared__ __align__(16) unsigned short As[128 * 72];  // padded stride 72 (144B, 16B-aligned)
  __shared__ __align__(16) unsigned short Bs[128 * 64];
  const int tid = threadIdx.x;
  const int wave = tid >> 6, lane = tid & 63;
  const int r = lane & 15, quad = lane >> 4;
  const int wm = (wave >> 1) * 64, wn = (wave & 1) * 64;
  const int m0 = blockIdx.x * 128, n0 = blockIdx.y * 128;

  // B staging (async, 4 slabs per wave)
  const int srow = lane >> 3, scol = (lane & 7) * 8;
  const unsigned short* Bg[4];
  unsigned short* Bl[4];
  #pragma unroll
  for (int li = 0; li < 4; li++) {
    int row = wave * 32 + li * 8 + srow;
    Bg[li] = wob + (size_t)(n0 + row) * DIMK + scol;
    Bl[li] = &Bs[(wave * 4 + li) * 512];
  }

  // A transform indices: 2 threads per token row, 32 dims each
  const int trow = tid >> 1, half = tid & 1;
  const int tg = m0 + trow;
  const int b = tg >> 13, pos = tg & 8191;
  const unsigned short* qrow = qkv + (size_t)tg * 1024 + half * 32;
  const float2* rp = rope + pos * 32 + half * 16;
  unsigned short* aw = &As[trow * 72 + half * 32];

  floatx4 acc[4][4];
  #pragma unroll
  for (int i = 0; i < 4; i++)
    #pragma unroll
    for (int j = 0; j < 4; j++)
      acc[i][j] = (floatx4){0.f, 0.f, 0.f, 0.f};

  for (int h = 0; h < 8; h++) {
    #pragma unroll
    for (int li = 0; li < 4; li++)
      gload_lds16(Bg[li] + h * 64, Bl[li]);

    const int bk = b * 4 + (h >> 1);
    const float* Ks = Ksum + bk * 64 + half * 32;
    const float* Kv = KV + bk * 64 + half * 32;
    const unsigned int* qu = (const unsigned int*)(qrow + h * 64);
    float fr[16], fi[16];
    float z = 0.f;
    #pragma unroll
    for (int j = 0; j < 16; j++) {
      unsigned int qp = qu[j];
      float qx = bf2f((unsigned short)(qp & 0xffffu));
      float qy = bf2f((unsigned short)(qp >> 16));
      float2 cs = rp[j];
      float ar = qx * cs.x - qy * cs.y;
      float ai = qx * cs.y + qy * cs.x;
      ar = ar > 0.f ? ar + 1.f : __expf(ar);
      ai = ai > 0.f ? ai + 1.f : __expf(ai);
      fr[j] = ar; fi[j] = ai;
      z += ar * Ks[2 * j] + ai * Ks[2 * j + 1];
    }
    z += __shfl_xor(z, 1, 64);  // partner thread of same token
    float inv = 1.0f / (z + 1e-6f);
    uint4 pk[4];
    #pragma unroll
    for (int g = 0; g < 4; g++) {
      unsigned int wd[4];
      #pragma unroll
      for (int jj = 0; jj < 4; jj++) {
        int j = g * 4 + jj;
        float y0 = fr[j] * Kv[2 * j] * inv;
        float y1 = fi[j] * Kv[2 * j + 1] * inv;
        wd[jj] = (unsigned int)f2bf(y0) | ((unsigned int)f2bf(y1) << 16);
      }
      pk[g] = make_uint4(wd[0], wd[1], wd[2], wd[3]);
    }
    #pragma unroll
    for (int g = 0; g < 4; g++)
      *(uint4*)(aw + g * 8) = pk[g];

    __syncthreads();  // drains B-DMA (vmcnt) + A LDS writes (lgkm)
    #pragma unroll
    for (int kk = 0; kk < 64; kk += 32) {
      short8 af[4], bfv[4];
      #pragma unroll
      for (int i = 0; i < 4; i++)
        af[i] = *(const short8*)&As[(wm + i * 16 + r) * 72 + kk + quad * 8];
      #pragma unroll
      for (int j = 0; j < 4; j++)
        bfv[j] = *(const short8*)&Bs[(wn + j * 16 + r) * 64 + kk + quad * 8];
      #pragma unroll
      for (int i = 0; i < 4; i++)
        #pragma unroll
        for (int j = 0; j < 4; j++)
          acc[i][j] = __builtin_amdgcn_mfma_f32_16x16x32_bf16(af[i], bfv[j], acc[i][j], 0, 0, 0);
    }
    __syncthreads();  // protect As/Bs before next slice overwrites
  }
  #pragma unroll
  for (int i = 0; i < 4; i++)
    #pragma unroll
    for (int j = 0; j < 4; j++) {
      int row = m0 + wm + i * 16 + quad * 4;
      int col = n0 + wn + j * 16 + r;
      #pragma unroll
      for (int p = 0; p < 4; p++)
        C[(size_t)(row + p) * N + col] = acc[i][j][p];
    }
}

extern "C" void kernel_launch(void* const* d_in, const int* in_sizes, int n_in,
                              void* d_out, int out_size, void* d_ws, size_t ws_size,
                              hipStream_t stream) {
  const float* x = (const float*)d_in[0];
  const float* norm_w = (const float*)d_in[1];
  const float* wq = (const float*)d_in[2];
  const float* wk = (const float*)d_in[3];
  const float* wv = (const float*)d_in[4];
  const float* wo = (const float*)d_in[5];
  float* out = (float*)d_out;

  char* ws = (char*)d_ws;
  unsigned short* xn  = (unsigned short*)(ws);                  // 33,554,432 B
  unsigned short* Wb  = (unsigned short*)(ws + 33554432);       //  1,048,576 B
  unsigned short* wob = (unsigned short*)(ws + 34603008);       //    524,288 B
  unsigned short* qkv = (unsigned short*)(ws + 35127296);       // 67,108,864 B
  float2* rope        = (float2*)(ws + 102236160);              //  2,097,152 B
  float* KV           = (float*)(ws + 104333312);               //      4,096 B
  float* Ksum         = (float*)(ws + 104337408);               //      4,096 B

  k_setup<<<2048, 256, 0, stream>>>(wq, wk, wv, wo, Wb, wob, rope, KV);
  k_rmsnorm<<<8192, 256, 0, stream>>>(x, norm_w, xn);
  k_gemm128<<<dim3(256, 8), 256, 0, stream>>>(xn, Wb, qkv, 1024);
  k_kvred<<<dim3(32, 16), 256, 0, stream>>>(qkv, rope, KV, Ksum);
  k_gemm_out<<<dim3(256, 4), 256, 0, stream>>>(qkv, wob, rope, KV, Ksum, out);
}

// Round 4
// 267.161 us; speedup vs baseline: 1.1396x; 1.1396x over previous
//
#include <hip/hip_runtime.h>
#include <cmath>

typedef __attribute__((ext_vector_type(8))) short short8;
typedef __attribute__((ext_vector_type(4))) float floatx4;

#define T_TOK 32768
#define DIMK 512

__device__ __forceinline__ unsigned short f2bf(float f) {
  union { float f; unsigned int u; } v; v.f = f;
  unsigned int r = (v.u + 0x7fffu + ((v.u >> 16) & 1u)) >> 16;
  return (unsigned short)r;
}
__device__ __forceinline__ float bf2f(unsigned short h) {
  union { unsigned int u; float f; } v; v.u = ((unsigned int)h) << 16;
  return v.f;
}

// async global->LDS 16B per lane: HW writes lane i at ldsbase + i*16
__device__ __forceinline__ void gload_lds16(const unsigned short* g, unsigned short* ldsbase) {
  __builtin_amdgcn_global_load_lds(
      (const __attribute__((address_space(1))) unsigned int*)g,
      (__attribute__((address_space(3))) unsigned int*)ldsbase, 16, 0, 0);
}

// ------- setup: weight bf16 convert + rope table + KV/Ksum zero (one launch) -------
__global__ __launch_bounds__(256) void k_setup(const float* __restrict__ wq,
    const float* __restrict__ wk, const float* __restrict__ wv,
    const float* __restrict__ wo, unsigned short* __restrict__ Wb,
    unsigned short* __restrict__ wob, float2* __restrict__ rope,
    float* __restrict__ KVz) {
  int i = blockIdx.x * 256 + threadIdx.x;  // 524288
  float v;
  if (i < 262144) v = wq[i];
  else if (i < 393216) v = wk[i - 262144];
  else v = wv[i - 393216];
  Wb[i] = f2bf(v);
  if (i < 262144) {
    wob[i] = f2bf(wo[i]);
    // rope: inv[m] = 10^(-m/8) exact double mul chain; range-reduce mod 2pi in f64
    int s = i >> 5, m = i & 31;
    const double c0 = 0.74989420933245582;   // 10^(-1/8)
    double c1 = c0 * c0, c2 = c1 * c1, c3 = c2 * c2, c4 = c3 * c3;
    double p = 1.0;
    if (m & 1)  p *= c0;
    if (m & 2)  p *= c1;
    if (m & 4)  p *= c2;
    if (m & 8)  p *= c3;
    if (m & 16) p *= c4;
    double ang = (double)s * p;
    const double TWO_PI = 6.2831853071795864769;
    double q = rint(ang * (1.0 / TWO_PI));
    double r = fma(-q, TWO_PI, ang);
    float rf = (float)r;
    rope[i] = make_float2(cosf(rf), sinf(rf));
  }
  if (i < 2048) KVz[i] = 0.f;
}

// ------- RMSNorm: one wave per token, float4 loads, no LDS -------
__global__ __launch_bounds__(256) void k_rmsnorm(const float* __restrict__ x,
    const float* __restrict__ w, unsigned short* __restrict__ xn) {
  int wave = threadIdx.x >> 6, lane = threadIdx.x & 63;
  size_t t = (size_t)blockIdx.x * 4 + wave;
  const float4* xr = (const float4*)(x + t * DIMK);
  float4 a = xr[lane * 2];
  float4 b = xr[lane * 2 + 1];
  float ss = a.x * a.x + a.y * a.y + a.z * a.z + a.w * a.w
           + b.x * b.x + b.y * b.y + b.z * b.z + b.w * b.w;
  #pragma unroll
  for (int off = 32; off >= 1; off >>= 1) ss += __shfl_xor(ss, off, 64);
  float scale = rsqrtf(ss * (1.0f / DIMK) + 1e-6f);
  const float4* wr = (const float4*)w;
  float4 w0 = wr[lane * 2], w1 = wr[lane * 2 + 1];
  uint4 o;
  o.x = (unsigned int)f2bf(a.x * scale * w0.x) | ((unsigned int)f2bf(a.y * scale * w0.y) << 16);
  o.y = (unsigned int)f2bf(a.z * scale * w0.z) | ((unsigned int)f2bf(a.w * scale * w0.w) << 16);
  o.z = (unsigned int)f2bf(b.x * scale * w1.x) | ((unsigned int)f2bf(b.y * scale * w1.y) << 16);
  o.w = (unsigned int)f2bf(b.z * scale * w1.z) | ((unsigned int)f2bf(b.w * scale * w1.w) << 16);
  *(uint4*)(xn + t * DIMK + lane * 8) = o;
}

// ------- GEMM: C(M,N) = A(M,512) * Bw(N,512)^T -------
// 128x128 tile, BK=64, global_load_lds width=16, 4 waves x 4x4 16x16x32 MFMA.
// blockIdx.x = ROW tile (fast dim): blocks sharing an A tile land on one XCD.
template <bool BF16_OUT>
__global__ __launch_bounds__(256) void k_gemm128(const unsigned short* __restrict__ A,
    const unsigned short* __restrict__ Bw, void* __restrict__ Cv, int N) {
  constexpr int K = DIMK;
  constexpr int BK = 64;
  __shared__ __align__(16) unsigned short As[128 * BK];
  __shared__ __align__(16) unsigned short Bs[128 * BK];
  const int tid = threadIdx.x;
  const int wave = tid >> 6, lane = tid & 63;
  const int r = lane & 15, quad = lane >> 4;
  const int wm = (wave >> 1) * 64, wn = (wave & 1) * 64;
  const int m0 = blockIdx.x * 128, n0 = blockIdx.y * 128;

  const int srow = (lane >> 3);
  const int scol = (lane & 7) * 8;
  const unsigned short* Ag[4];
  const unsigned short* Bg[4];
  unsigned short* Al[4];
  unsigned short* Bl[4];
  #pragma unroll
  for (int li = 0; li < 4; li++) {
    int row = wave * 32 + li * 8 + srow;
    Ag[li] = A  + (size_t)(m0 + row) * K + scol;
    Bg[li] = Bw + (size_t)(n0 + row) * K + scol;
    Al[li] = &As[(wave * 4 + li) * 512];
    Bl[li] = &Bs[(wave * 4 + li) * 512];
  }

  floatx4 acc[4][4];
  #pragma unroll
  for (int i = 0; i < 4; i++)
    #pragma unroll
    for (int j = 0; j < 4; j++)
      acc[i][j] = (floatx4){0.f, 0.f, 0.f, 0.f};

  for (int k0 = 0; k0 < K; k0 += BK) {
    #pragma unroll
    for (int li = 0; li < 4; li++) {
      gload_lds16(Ag[li] + k0, Al[li]);
      gload_lds16(Bg[li] + k0, Bl[li]);
    }
    __syncthreads();
    #pragma unroll
    for (int kk = 0; kk < BK; kk += 32) {
      short8 af[4], bfv[4];
      #pragma unroll
      for (int i = 0; i < 4; i++)
        af[i] = *(const short8*)&As[(wm + i * 16 + r) * BK + kk + quad * 8];
      #pragma unroll
      for (int j = 0; j < 4; j++)
        bfv[j] = *(const short8*)&Bs[(wn + j * 16 + r) * BK + kk + quad * 8];
      #pragma unroll
      for (int i = 0; i < 4; i++)
        #pragma unroll
        for (int j = 0; j < 4; j++)
          acc[i][j] = __builtin_amdgcn_mfma_f32_16x16x32_bf16(af[i], bfv[j], acc[i][j], 0, 0, 0);
    }
    __syncthreads();
  }
  // C/D layout: col = lane&15, row = quad*4 + p
  #pragma unroll
  for (int i = 0; i < 4; i++)
    #pragma unroll
    for (int j = 0; j < 4; j++) {
      int row = m0 + wm + i * 16 + quad * 4;
      int col = n0 + wn + j * 16 + r;
      #pragma unroll
      for (int p = 0; p < 4; p++) {
        if constexpr (BF16_OUT) {
          ((unsigned short*)Cv)[(size_t)(row + p) * N + col] = f2bf(acc[i][j][p]);
        } else {
          ((float*)Cv)[(size_t)(row + p) * N + col] = acc[i][j][p];
        }
      }
    }
}

// ------- KV / Ksum reduction over sequence -------
__global__ __launch_bounds__(256) void k_kvred(const unsigned short* __restrict__ qkv,
    const float2* __restrict__ rope, float* __restrict__ KV, float* __restrict__ Ksum) {
  int bk = blockIdx.y;
  int b = bk >> 2, kh = bk & 3;
  int tid = threadIdx.x;
  int m = tid & 31;
  int sl = tid >> 5;
  int s0 = blockIdx.x * 256;
  float kvr = 0.f, kvi = 0.f, ksr = 0.f, ksi = 0.f;
  for (int si = sl; si < 256; si += 8) {
    int s = s0 + si;
    size_t t = (size_t)b * 8192 + s;
    const unsigned short* base = qkv + t * 1024;
    unsigned int kp = *(const unsigned int*)(base + 512 + kh * 64 + 2 * m);
    unsigned int vp = *(const unsigned int*)(base + 768 + kh * 64 + 2 * m);
    float kx = bf2f((unsigned short)(kp & 0xffffu));
    float ky = bf2f((unsigned short)(kp >> 16));
    float vx = bf2f((unsigned short)(vp & 0xffffu));
    float vy = bf2f((unsigned short)(vp >> 16));
    float2 cs = rope[s * 32 + m];
    float kr = kx * cs.x - ky * cs.y;
    float ki = kx * cs.y + ky * cs.x;
    kr = kr > 0.f ? kr + 1.f : __expf(kr);
    ki = ki > 0.f ? ki + 1.f : __expf(ki);
    kvr += kr * vx; kvi += ki * vy;
    ksr += kr;      ksi += ki;
  }
  __shared__ float red[256 * 4];
  red[tid * 4 + 0] = kvr; red[tid * 4 + 1] = kvi;
  red[tid * 4 + 2] = ksr; red[tid * 4 + 3] = ksi;
  __syncthreads();
  if (sl == 0) {
    for (int q = 1; q < 8; q++) {
      kvr += red[(q * 32 + m) * 4 + 0]; kvi += red[(q * 32 + m) * 4 + 1];
      ksr += red[(q * 32 + m) * 4 + 2]; ksi += red[(q * 32 + m) * 4 + 3];
    }
    atomicAdd(&KV[bk * 64 + 2 * m], kvr);
    atomicAdd(&KV[bk * 64 + 2 * m + 1], kvi);
    atomicAdd(&Ksum[bk * 64 + 2 * m], ksr);
    atomicAdd(&Ksum[bk * 64 + 2 * m + 1], ksi);
  }
}

// ------- Q path: rope+phi, Z, Y -> bf16 (one block per token, wave per head) -------
__global__ __launch_bounds__(512) void k_qkern(const unsigned short* __restrict__ qkv,
    const float2* __restrict__ rope, const float* __restrict__ KV,
    const float* __restrict__ Ksum, unsigned short* __restrict__ Yb) {
  int t = blockIdx.x;
  int tid = threadIdx.x;
  int h = tid >> 6, lane = tid & 63;
  int b = t >> 13, pos = t & 8191;
  float q = bf2f(qkv[(size_t)t * 1024 + h * 64 + lane]);
  float2 cs = rope[pos * 32 + (lane >> 1)];
  float partner = __shfl_xor(q, 1, 64);
  float qr = ((lane & 1) == 0) ? (q * cs.x - partner * cs.y)
                               : (partner * cs.y + q * cs.x);
  float ql = qr > 0.f ? qr + 1.f : __expf(qr);
  int bk = b * 4 + (h >> 1);
  float z = ql * Ksum[bk * 64 + lane];
  #pragma unroll
  for (int off = 32; off >= 1; off >>= 1) z += __shfl_xor(z, off, 64);
  float y = ql * KV[bk * 64 + lane] / (z + 1e-6f);
  Yb[(size_t)t * 512 + h * 64 + lane] = f2bf(y);
}

extern "C" void kernel_launch(void* const* d_in, const int* in_sizes, int n_in,
                              void* d_out, int out_size, void* d_ws, size_t ws_size,
                              hipStream_t stream) {
  const float* x = (const float*)d_in[0];
  const float* norm_w = (const float*)d_in[1];
  const float* wq = (const float*)d_in[2];
  const float* wk = (const float*)d_in[3];
  const float* wv = (const float*)d_in[4];
  const float* wo = (const float*)d_in[5];
  float* out = (float*)d_out;

  char* ws = (char*)d_ws;
  unsigned short* xn  = (unsigned short*)(ws);                  // 33,554,432 B
  unsigned short* Wb  = (unsigned short*)(ws + 33554432);       //  1,048,576 B
  unsigned short* wob = (unsigned short*)(ws + 34603008);       //    524,288 B
  unsigned short* qkv = (unsigned short*)(ws + 35127296);       // 67,108,864 B
  float2* rope        = (float2*)(ws + 102236160);              //  2,097,152 B
  float* KV           = (float*)(ws + 104333312);               //      4,096 B
  float* Ksum         = (float*)(ws + 104337408);               //      4,096 B
  unsigned short* Yb  = (unsigned short*)(ws + 104341504);      // 33,554,432 B

  k_setup<<<2048, 256, 0, stream>>>(wq, wk, wv, wo, Wb, wob, rope, KV);
  k_rmsnorm<<<8192, 256, 0, stream>>>(x, norm_w, xn);
  k_gemm128<true><<<dim3(256, 8), 256, 0, stream>>>(xn, Wb, (void*)qkv, 1024);
  k_kvred<<<dim3(32, 16), 256, 0, stream>>>(qkv, rope, KV, Ksum);
  k_qkern<<<T_TOK, 512, 0, stream>>>(qkv, rope, KV, Ksum, Yb);
  k_gemm128<false><<<dim3(256, 4), 256, 0, stream>>>(Yb, wob, (void*)out, 512);
}

// Round 5
// 248.105 us; speedup vs baseline: 1.2272x; 1.0768x over previous
//
#include <hip/hip_runtime.h>
#include <cmath>

typedef __attribute__((ext_vector_type(8))) short short8;
typedef __attribute__((ext_vector_type(4))) float floatx4;

#define T_TOK 32768
#define DIMK 512

__device__ __forceinline__ unsigned short f2bf(float f) {
  union { float f; unsigned int u; } v; v.f = f;
  unsigned int r = (v.u + 0x7fffu + ((v.u >> 16) & 1u)) >> 16;
  return (unsigned short)r;
}
__device__ __forceinline__ float bf2f(unsigned short h) {
  union { unsigned int u; float f; } v; v.u = ((unsigned int)h) << 16;
  return v.f;
}

// async global->LDS 16B per lane: HW writes lane i at ldsbase + i*16
__device__ __forceinline__ void gload_lds16(const unsigned short* g, unsigned short* ldsbase) {
  __builtin_amdgcn_global_load_lds(
      (const __attribute__((address_space(1))) unsigned int*)g,
      (__attribute__((address_space(3))) unsigned int*)ldsbase, 16, 0, 0);
}

// ------- setup: weight bf16 convert + rope table + KV/Ksum zero (one launch) -------
__global__ __launch_bounds__(256) void k_setup(const float* __restrict__ wq,
    const float* __restrict__ wk, const float* __restrict__ wv,
    const float* __restrict__ wo, unsigned short* __restrict__ Wb,
    unsigned short* __restrict__ wob, float2* __restrict__ rope,
    float* __restrict__ KVz) {
  int i = blockIdx.x * 256 + threadIdx.x;  // 524288
  float v;
  if (i < 262144) v = wq[i];
  else if (i < 393216) v = wk[i - 262144];
  else v = wv[i - 393216];
  Wb[i] = f2bf(v);
  if (i < 262144) {
    wob[i] = f2bf(wo[i]);
    // rope: inv[m] = 10^(-m/8) exact double mul chain; range-reduce mod 2pi in f64
    int s = i >> 5, m = i & 31;
    const double c0 = 0.74989420933245582;   // 10^(-1/8)
    double c1 = c0 * c0, c2 = c1 * c1, c3 = c2 * c2, c4 = c3 * c3;
    double p = 1.0;
    if (m & 1)  p *= c0;
    if (m & 2)  p *= c1;
    if (m & 4)  p *= c2;
    if (m & 8)  p *= c3;
    if (m & 16) p *= c4;
    double ang = (double)s * p;
    const double TWO_PI = 6.2831853071795864769;
    double q = rint(ang * (1.0 / TWO_PI));
    double r = fma(-q, TWO_PI, ang);
    float rf = (float)r;
    rope[i] = make_float2(cosf(rf), sinf(rf));
  }
  if (i < 2048) KVz[i] = 0.f;
}

// ------- RMSNorm: one wave per token, float4 loads, no LDS -------
__global__ __launch_bounds__(256) void k_rmsnorm(const float* __restrict__ x,
    const float* __restrict__ w, unsigned short* __restrict__ xn) {
  int wave = threadIdx.x >> 6, lane = threadIdx.x & 63;
  size_t t = (size_t)blockIdx.x * 4 + wave;
  const float4* xr = (const float4*)(x + t * DIMK);
  float4 a = xr[lane * 2];
  float4 b = xr[lane * 2 + 1];
  float ss = a.x * a.x + a.y * a.y + a.z * a.z + a.w * a.w
           + b.x * b.x + b.y * b.y + b.z * b.z + b.w * b.w;
  #pragma unroll
  for (int off = 32; off >= 1; off >>= 1) ss += __shfl_xor(ss, off, 64);
  float scale = rsqrtf(ss * (1.0f / DIMK) + 1e-6f);
  const float4* wr = (const float4*)w;
  float4 w0 = wr[lane * 2], w1 = wr[lane * 2 + 1];
  uint4 o;
  o.x = (unsigned int)f2bf(a.x * scale * w0.x) | ((unsigned int)f2bf(a.y * scale * w0.y) << 16);
  o.y = (unsigned int)f2bf(a.z * scale * w0.z) | ((unsigned int)f2bf(a.w * scale * w0.w) << 16);
  o.z = (unsigned int)f2bf(b.x * scale * w1.x) | ((unsigned int)f2bf(b.y * scale * w1.y) << 16);
  o.w = (unsigned int)f2bf(b.z * scale * w1.z) | ((unsigned int)f2bf(b.w * scale * w1.w) << 16);
  *(uint4*)(xn + t * DIMK + lane * 8) = o;
}

// ------- GEMM: C(M,N) = A(M,512) * Bw(N,512)^T -------
// 128x128 tile, BK=64, global_load_lds width=16, 4 waves x 4x4 16x16x32 MFMA.
// blockIdx.x = ROW tile (fast dim): blocks sharing an A tile land on one XCD.
// LDS layout XOR-swizzled: LDS[R][cblk] = global[R][cblk ^ (R&7)] -- DMA-compatible
// (lane fetches the swizzled global block) and bank-conflict-free reads
// (within a 16-lane quarter-wave, 8 distinct 4-bank groups x 2 lanes = 2-way = free).
template <bool BF16_OUT>
__global__ __launch_bounds__(256) void k_gemm128(const unsigned short* __restrict__ A,
    const unsigned short* __restrict__ Bw, void* __restrict__ Cv, int N) {
  constexpr int K = DIMK;
  constexpr int BK = 64;
  __shared__ __align__(16) unsigned short As[128 * BK];
  __shared__ __align__(16) unsigned short Bs[128 * BK];
  const int tid = threadIdx.x;
  const int wave = tid >> 6, lane = tid & 63;
  const int r = lane & 15, quad = lane >> 4;
  const int wm = (wave >> 1) * 64, wn = (wave & 1) * 64;
  const int m0 = blockIdx.x * 128, n0 = blockIdx.y * 128;

  const int srow = (lane >> 3);                 // row within 8-row slab
  const int scol = (((lane & 7) ^ srow)) * 8;   // swizzled global col-block (shorts)
  const unsigned short* Ag[4];
  const unsigned short* Bg[4];
  unsigned short* Al[4];
  unsigned short* Bl[4];
  #pragma unroll
  for (int li = 0; li < 4; li++) {
    int row = wave * 32 + li * 8 + srow;
    Ag[li] = A  + (size_t)(m0 + row) * K + scol;
    Bg[li] = Bw + (size_t)(n0 + row) * K + scol;
    Al[li] = &As[(wave * 4 + li) * 512];
    Bl[li] = &Bs[(wave * 4 + li) * 512];
  }

  floatx4 acc[4][4];
  #pragma unroll
  for (int i = 0; i < 4; i++)
    #pragma unroll
    for (int j = 0; j < 4; j++)
      acc[i][j] = (floatx4){0.f, 0.f, 0.f, 0.f};

  const int r7 = r & 7;
  for (int k0 = 0; k0 < K; k0 += BK) {
    #pragma unroll
    for (int li = 0; li < 4; li++) {
      gload_lds16(Ag[li] + k0, Al[li]);
      gload_lds16(Bg[li] + k0, Bl[li]);
    }
    __syncthreads();
    #pragma unroll
    for (int kk = 0; kk < BK; kk += 32) {
      const int sw = ((((kk >> 3) + quad) ^ r7)) * 8;  // swizzled col offset (shorts)
      short8 af[4], bfv[4];
      #pragma unroll
      for (int i = 0; i < 4; i++)
        af[i] = *(const short8*)&As[(wm + i * 16 + r) * BK + sw];
      #pragma unroll
      for (int j = 0; j < 4; j++)
        bfv[j] = *(const short8*)&Bs[(wn + j * 16 + r) * BK + sw];
      #pragma unroll
      for (int i = 0; i < 4; i++)
        #pragma unroll
        for (int j = 0; j < 4; j++)
          acc[i][j] = __builtin_amdgcn_mfma_f32_16x16x32_bf16(af[i], bfv[j], acc[i][j], 0, 0, 0);
    }
    __syncthreads();
  }
  // C/D layout: col = lane&15, row = quad*4 + p
  #pragma unroll
  for (int i = 0; i < 4; i++)
    #pragma unroll
    for (int j = 0; j < 4; j++) {
      int row = m0 + wm + i * 16 + quad * 4;
      int col = n0 + wn + j * 16 + r;
      #pragma unroll
      for (int p = 0; p < 4; p++) {
        if constexpr (BF16_OUT) {
          ((unsigned short*)Cv)[(size_t)(row + p) * N + col] = f2bf(acc[i][j][p]);
        } else {
          ((float*)Cv)[(size_t)(row + p) * N + col] = acc[i][j][p];
        }
      }
    }
}

// ------- KV / Ksum reduction over sequence -------
__global__ __launch_bounds__(256) void k_kvred(const unsigned short* __restrict__ qkv,
    const float2* __restrict__ rope, float* __restrict__ KV, float* __restrict__ Ksum) {
  int bk = blockIdx.y;
  int b = bk >> 2, kh = bk & 3;
  int tid = threadIdx.x;
  int m = tid & 31;
  int sl = tid >> 5;
  int s0 = blockIdx.x * 256;
  float kvr = 0.f, kvi = 0.f, ksr = 0.f, ksi = 0.f;
  for (int si = sl; si < 256; si += 8) {
    int s = s0 + si;
    size_t t = (size_t)b * 8192 + s;
    const unsigned short* base = qkv + t * 1024;
    unsigned int kp = *(const unsigned int*)(base + 512 + kh * 64 + 2 * m);
    unsigned int vp = *(const unsigned int*)(base + 768 + kh * 64 + 2 * m);
    float kx = bf2f((unsigned short)(kp & 0xffffu));
    float ky = bf2f((unsigned short)(kp >> 16));
    float vx = bf2f((unsigned short)(vp & 0xffffu));
    float vy = bf2f((unsigned short)(vp >> 16));
    float2 cs = rope[s * 32 + m];
    float kr = kx * cs.x - ky * cs.y;
    float ki = kx * cs.y + ky * cs.x;
    kr = kr > 0.f ? kr + 1.f : __expf(kr);
    ki = ki > 0.f ? ki + 1.f : __expf(ki);
    kvr += kr * vx; kvi += ki * vy;
    ksr += kr;      ksi += ki;
  }
  __shared__ float red[256 * 4];
  red[tid * 4 + 0] = kvr; red[tid * 4 + 1] = kvi;
  red[tid * 4 + 2] = ksr; red[tid * 4 + 3] = ksi;
  __syncthreads();
  if (sl == 0) {
    for (int q = 1; q < 8; q++) {
      kvr += red[(q * 32 + m) * 4 + 0]; kvi += red[(q * 32 + m) * 4 + 1];
      ksr += red[(q * 32 + m) * 4 + 2]; ksi += red[(q * 32 + m) * 4 + 3];
    }
    atomicAdd(&KV[bk * 64 + 2 * m], kvr);
    atomicAdd(&KV[bk * 64 + 2 * m + 1], kvi);
    atomicAdd(&Ksum[bk * 64 + 2 * m], ksr);
    atomicAdd(&Ksum[bk * 64 + 2 * m + 1], ksi);
  }
}

// ------- Q path: rope+phi, Z, Y -> bf16 (one block per token, wave per head) -------
__global__ __launch_bounds__(512) void k_qkern(const unsigned short* __restrict__ qkv,
    const float2* __restrict__ rope, const float* __restrict__ KV,
    const float* __restrict__ Ksum, unsigned short* __restrict__ Yb) {
  int t = blockIdx.x;
  int tid = threadIdx.x;
  int h = tid >> 6, lane = tid & 63;
  int b = t >> 13, pos = t & 8191;
  float q = bf2f(qkv[(size_t)t * 1024 + h * 64 + lane]);
  float2 cs = rope[pos * 32 + (lane >> 1)];
  float partner = __shfl_xor(q, 1, 64);
  float qr = ((lane & 1) == 0) ? (q * cs.x - partner * cs.y)
                               : (partner * cs.y + q * cs.x);
  float ql = qr > 0.f ? qr + 1.f : __expf(qr);
  int bk = b * 4 + (h >> 1);
  float z = ql * Ksum[bk * 64 + lane];
  #pragma unroll
  for (int off = 32; off >= 1; off >>= 1) z += __shfl_xor(z, off, 64);
  float y = ql * KV[bk * 64 + lane] / (z + 1e-6f);
  Yb[(size_t)t * 512 + h * 64 + lane] = f2bf(y);
}

extern "C" void kernel_launch(void* const* d_in, const int* in_sizes, int n_in,
                              void* d_out, int out_size, void* d_ws, size_t ws_size,
                              hipStream_t stream) {
  const float* x = (const float*)d_in[0];
  const float* norm_w = (const float*)d_in[1];
  const float* wq = (const float*)d_in[2];
  const float* wk = (const float*)d_in[3];
  const float* wv = (const float*)d_in[4];
  const float* wo = (const float*)d_in[5];
  float* out = (float*)d_out;

  char* ws = (char*)d_ws;
  unsigned short* xn  = (unsigned short*)(ws);                  // 33,554,432 B
  unsigned short* Wb  = (unsigned short*)(ws + 33554432);       //  1,048,576 B
  unsigned short* wob = (unsigned short*)(ws + 34603008);       //    524,288 B
  unsigned short* qkv = (unsigned short*)(ws + 35127296);       // 67,108,864 B
  float2* rope        = (float2*)(ws + 102236160);              //  2,097,152 B
  float* KV           = (float*)(ws + 104333312);               //      4,096 B
  float* Ksum         = (float*)(ws + 104337408);               //      4,096 B
  unsigned short* Yb  = (unsigned short*)(ws + 104341504);      // 33,554,432 B

  k_setup<<<2048, 256, 0, stream>>>(wq, wk, wv, wo, Wb, wob, rope, KV);
  k_rmsnorm<<<8192, 256, 0, stream>>>(x, norm_w, xn);
  k_gemm128<true><<<dim3(256, 8), 256, 0, stream>>>(xn, Wb, (void*)qkv, 1024);
  k_kvred<<<dim3(32, 16), 256, 0, stream>>>(qkv, rope, KV, Ksum);
  k_qkern<<<T_TOK, 512, 0, stream>>>(qkv, rope, KV, Ksum, Yb);
  k_gemm128<false><<<dim3(256, 4), 256, 0, stream>>>(Yb, wob, (void*)out, 512);
}

// Round 6
// 232.396 us; speedup vs baseline: 1.3101x; 1.0676x over previous
//
#include <hip/hip_runtime.h>
#include <cmath>

typedef __attribute__((ext_vector_type(8))) short short8;
typedef __attribute__((ext_vector_type(4))) float floatx4;

#define T_TOK 32768
#define DIMK 512

__device__ __forceinline__ unsigned short f2bf(float f) {
  union { float f; unsigned int u; } v; v.f = f;
  unsigned int r = (v.u + 0x7fffu + ((v.u >> 16) & 1u)) >> 16;
  return (unsigned short)r;
}
__device__ __forceinline__ float bf2f(unsigned short h) {
  union { unsigned int u; float f; } v; v.u = ((unsigned int)h) << 16;
  return v.f;
}

// async global->LDS 16B per lane: HW writes lane i at ldsbase + i*16
__device__ __forceinline__ void gload_lds16(const unsigned short* g, unsigned short* ldsbase) {
  __builtin_amdgcn_global_load_lds(
      (const __attribute__((address_space(1))) unsigned int*)g,
      (__attribute__((address_space(3))) unsigned int*)ldsbase, 16, 0, 0);
}

// ------- prep: [blocks 0..2047] weights->bf16 + rope + zero; [2048..10239] rmsnorm -------
__global__ __launch_bounds__(256) void k_prep(const float* __restrict__ x,
    const float* __restrict__ norm_w, const float* __restrict__ wq,
    const float* __restrict__ wk, const float* __restrict__ wv,
    const float* __restrict__ wo, unsigned short* __restrict__ Wb,
    unsigned short* __restrict__ wob, float2* __restrict__ rope,
    float* __restrict__ KVz, unsigned short* __restrict__ xn) {
  if (blockIdx.x < 2048) {
    int i = blockIdx.x * 256 + threadIdx.x;  // 524288
    float v;
    if (i < 262144) v = wq[i];
    else if (i < 393216) v = wk[i - 262144];
    else v = wv[i - 393216];
    Wb[i] = f2bf(v);
    if (i < 262144) {
      wob[i] = f2bf(wo[i]);
      // rope: inv[m] = 10^(-m/8) exact double mul chain; range-reduce mod 2pi in f64
      int s = i >> 5, m = i & 31;
      const double c0 = 0.74989420933245582;   // 10^(-1/8)
      double c1 = c0 * c0, c2 = c1 * c1, c3 = c2 * c2, c4 = c3 * c3;
      double p = 1.0;
      if (m & 1)  p *= c0;
      if (m & 2)  p *= c1;
      if (m & 4)  p *= c2;
      if (m & 8)  p *= c3;
      if (m & 16) p *= c4;
      double ang = (double)s * p;
      const double TWO_PI = 6.2831853071795864769;
      double q = rint(ang * (1.0 / TWO_PI));
      double r = fma(-q, TWO_PI, ang);
      float rf = (float)r;
      rope[i] = make_float2(cosf(rf), sinf(rf));
    }
    if (i < 2048) KVz[i] = 0.f;
  } else {
    // rmsnorm: one wave per token, float4 loads
    int bid = blockIdx.x - 2048;
    int wave = threadIdx.x >> 6, lane = threadIdx.x & 63;
    size_t t = (size_t)bid * 4 + wave;
    const float4* xr = (const float4*)(x + t * DIMK);
    float4 a = xr[lane * 2];
    float4 b = xr[lane * 2 + 1];
    float ss = a.x * a.x + a.y * a.y + a.z * a.z + a.w * a.w
             + b.x * b.x + b.y * b.y + b.z * b.z + b.w * b.w;
    #pragma unroll
    for (int off = 32; off >= 1; off >>= 1) ss += __shfl_xor(ss, off, 64);
    float scale = rsqrtf(ss * (1.0f / DIMK) + 1e-6f);
    const float4* wr = (const float4*)norm_w;
    float4 w0 = wr[lane * 2], w1 = wr[lane * 2 + 1];
    uint4 o;
    o.x = (unsigned int)f2bf(a.x * scale * w0.x) | ((unsigned int)f2bf(a.y * scale * w0.y) << 16);
    o.y = (unsigned int)f2bf(a.z * scale * w0.z) | ((unsigned int)f2bf(a.w * scale * w0.w) << 16);
    o.z = (unsigned int)f2bf(b.x * scale * w1.x) | ((unsigned int)f2bf(b.y * scale * w1.y) << 16);
    o.w = (unsigned int)f2bf(b.z * scale * w1.z) | ((unsigned int)f2bf(b.w * scale * w1.w) << 16);
    *(uint4*)(xn + t * DIMK + lane * 8) = o;
  }
}

// ------- GEMM: C(M,N) = A(M,512) * Bw(N,512)^T -------
// 128x128 tile, BK=64, global_load_lds width=16, 4 waves x 4x4 16x16x32 MFMA.
// blockIdx.x = ROW tile (fast dim): blocks sharing an A tile land on one XCD.
// LDS XOR-swizzled: LDS[R][cblk] = global[R][cblk ^ (R&7)] -- conflict-free (verified: 0).
template <bool BF16_OUT>
__global__ __launch_bounds__(256) void k_gemm128(const unsigned short* __restrict__ A,
    const unsigned short* __restrict__ Bw, void* __restrict__ Cv, int N) {
  constexpr int K = DIMK;
  constexpr int BK = 64;
  __shared__ __align__(16) unsigned short As[128 * BK];
  __shared__ __align__(16) unsigned short Bs[128 * BK];
  const int tid = threadIdx.x;
  const int wave = tid >> 6, lane = tid & 63;
  const int r = lane & 15, quad = lane >> 4;
  const int wm = (wave >> 1) * 64, wn = (wave & 1) * 64;
  const int m0 = blockIdx.x * 128, n0 = blockIdx.y * 128;

  const int srow = (lane >> 3);                 // row within 8-row slab
  const int scol = (((lane & 7) ^ srow)) * 8;   // swizzled global col-block (shorts)
  const unsigned short* Ag[4];
  const unsigned short* Bg[4];
  unsigned short* Al[4];
  unsigned short* Bl[4];
  #pragma unroll
  for (int li = 0; li < 4; li++) {
    int row = wave * 32 + li * 8 + srow;
    Ag[li] = A  + (size_t)(m0 + row) * K + scol;
    Bg[li] = Bw + (size_t)(n0 + row) * K + scol;
    Al[li] = &As[(wave * 4 + li) * 512];
    Bl[li] = &Bs[(wave * 4 + li) * 512];
  }

  floatx4 acc[4][4];
  #pragma unroll
  for (int i = 0; i < 4; i++)
    #pragma unroll
    for (int j = 0; j < 4; j++)
      acc[i][j] = (floatx4){0.f, 0.f, 0.f, 0.f};

  const int r7 = r & 7;
  for (int k0 = 0; k0 < K; k0 += BK) {
    #pragma unroll
    for (int li = 0; li < 4; li++) {
      gload_lds16(Ag[li] + k0, Al[li]);
      gload_lds16(Bg[li] + k0, Bl[li]);
    }
    __syncthreads();
    #pragma unroll
    for (int kk = 0; kk < BK; kk += 32) {
      const int sw = ((((kk >> 3) + quad) ^ r7)) * 8;  // swizzled col offset (shorts)
      short8 af[4], bfv[4];
      #pragma unroll
      for (int i = 0; i < 4; i++)
        af[i] = *(const short8*)&As[(wm + i * 16 + r) * BK + sw];
      #pragma unroll
      for (int j = 0; j < 4; j++)
        bfv[j] = *(const short8*)&Bs[(wn + j * 16 + r) * BK + sw];
      #pragma unroll
      for (int i = 0; i < 4; i++)
        #pragma unroll
        for (int j = 0; j < 4; j++)
          acc[i][j] = __builtin_amdgcn_mfma_f32_16x16x32_bf16(af[i], bfv[j], acc[i][j], 0, 0, 0);
    }
    __syncthreads();
  }
  // C/D layout: col = lane&15, row = quad*4 + p
  #pragma unroll
  for (int i = 0; i < 4; i++)
    #pragma unroll
    for (int j = 0; j < 4; j++) {
      int row = m0 + wm + i * 16 + quad * 4;
      int col = n0 + wn + j * 16 + r;
      #pragma unroll
      for (int p = 0; p < 4; p++) {
        if constexpr (BF16_OUT) {
          ((unsigned short*)Cv)[(size_t)(row + p) * N + col] = f2bf(acc[i][j][p]);
        } else {
          ((float*)Cv)[(size_t)(row + p) * N + col] = acc[i][j][p];
        }
      }
    }
}

// ------- KV / Ksum reduction over sequence -------
__global__ __launch_bounds__(256) void k_kvred(const unsigned short* __restrict__ qkv,
    const float2* __restrict__ rope, float* __restrict__ KV, float* __restrict__ Ksum) {
  int bk = blockIdx.y;
  int b = bk >> 2, kh = bk & 3;
  int tid = threadIdx.x;
  int m = tid & 31;
  int sl = tid >> 5;
  int s0 = blockIdx.x * 256;
  float kvr = 0.f, kvi = 0.f, ksr = 0.f, ksi = 0.f;
  for (int si = sl; si < 256; si += 8) {
    int s = s0 + si;
    size_t t = (size_t)b * 8192 + s;
    const unsigned short* base = qkv + t * 1024;
    unsigned int kp = *(const unsigned int*)(base + 512 + kh * 64 + 2 * m);
    unsigned int vp = *(const unsigned int*)(base + 768 + kh * 64 + 2 * m);
    float kx = bf2f((unsigned short)(kp & 0xffffu));
    float ky = bf2f((unsigned short)(kp >> 16));
    float vx = bf2f((unsigned short)(vp & 0xffffu));
    float vy = bf2f((unsigned short)(vp >> 16));
    float2 cs = rope[s * 32 + m];
    float kr = kx * cs.x - ky * cs.y;
    float ki = kx * cs.y + ky * cs.x;
    kr = kr > 0.f ? kr + 1.f : __expf(kr);
    ki = ki > 0.f ? ki + 1.f : __expf(ki);
    kvr += kr * vx; kvi += ki * vy;
    ksr += kr;      ksi += ki;
  }
  __shared__ float red[256 * 4];
  red[tid * 4 + 0] = kvr; red[tid * 4 + 1] = kvi;
  red[tid * 4 + 2] = ksr; red[tid * 4 + 3] = ksi;
  __syncthreads();
  if (sl == 0) {
    for (int q = 1; q < 8; q++) {
      kvr += red[(q * 32 + m) * 4 + 0]; kvi += red[(q * 32 + m) * 4 + 1];
      ksr += red[(q * 32 + m) * 4 + 2]; ksi += red[(q * 32 + m) * 4 + 3];
    }
    atomicAdd(&KV[bk * 64 + 2 * m], kvr);
    atomicAdd(&KV[bk * 64 + 2 * m + 1], kvi);
    atomicAdd(&Ksum[bk * 64 + 2 * m], ksr);
    atomicAdd(&Ksum[bk * 64 + 2 * m + 1], ksi);
  }
}

// ------- Q path: half-wave (32 lanes) per head, one uint pair per lane -------
__global__ __launch_bounds__(256) void k_qkern(const unsigned short* __restrict__ qkv,
    const float2* __restrict__ rope, const float* __restrict__ KV,
    const float* __restrict__ Ksum, unsigned short* __restrict__ Yb) {
  const int h = threadIdx.x >> 5;   // head 0..7
  const int pr = threadIdx.x & 31;  // rotation pair 0..31
  for (int t = blockIdx.x; t < T_TOK; t += gridDim.x) {
    int b = t >> 13, pos = t & 8191;
    unsigned int qp = *(const unsigned int*)(qkv + (size_t)t * 1024 + h * 64 + 2 * pr);
    float qx = bf2f((unsigned short)(qp & 0xffffu));
    float qy = bf2f((unsigned short)(qp >> 16));
    float2 cs = rope[pos * 32 + pr];
    float ar = qx * cs.x - qy * cs.y;
    float ai = qx * cs.y + qy * cs.x;
    ar = ar > 0.f ? ar + 1.f : __expf(ar);
    ai = ai > 0.f ? ai + 1.f : __expf(ai);
    int bk = b * 4 + (h >> 1);
    float2 ks = *(const float2*)(Ksum + bk * 64 + 2 * pr);
    float z = ar * ks.x + ai * ks.y;
    #pragma unroll
    for (int off = 16; off >= 1; off >>= 1) z += __shfl_xor(z, off, 64);  // stays in half-wave
    float2 kv = *(const float2*)(KV + bk * 64 + 2 * pr);
    float inv = 1.0f / (z + 1e-6f);
    unsigned int o = (unsigned int)f2bf(ar * kv.x * inv)
                   | ((unsigned int)f2bf(ai * kv.y * inv) << 16);
    *(unsigned int*)(Yb + (size_t)t * 512 + h * 64 + 2 * pr) = o;
  }
}

extern "C" void kernel_launch(void* const* d_in, const int* in_sizes, int n_in,
                              void* d_out, int out_size, void* d_ws, size_t ws_size,
                              hipStream_t stream) {
  const float* x = (const float*)d_in[0];
  const float* norm_w = (const float*)d_in[1];
  const float* wq = (const float*)d_in[2];
  const float* wk = (const float*)d_in[3];
  const float* wv = (const float*)d_in[4];
  const float* wo = (const float*)d_in[5];
  float* out = (float*)d_out;

  char* ws = (char*)d_ws;
  unsigned short* xn  = (unsigned short*)(ws);                  // 33,554,432 B
  unsigned short* Wb  = (unsigned short*)(ws + 33554432);       //  1,048,576 B
  unsigned short* wob = (unsigned short*)(ws + 34603008);       //    524,288 B
  unsigned short* qkv = (unsigned short*)(ws + 35127296);       // 67,108,864 B
  float2* rope        = (float2*)(ws + 102236160);              //  2,097,152 B
  float* KV           = (float*)(ws + 104333312);               //      4,096 B
  float* Ksum         = (float*)(ws + 104337408);               //      4,096 B
  unsigned short* Yb  = (unsigned short*)(ws + 104341504);      // 33,554,432 B

  k_prep<<<10240, 256, 0, stream>>>(x, norm_w, wq, wk, wv, wo, Wb, wob, rope, KV, xn);
  k_gemm128<true><<<dim3(256, 8), 256, 0, stream>>>(xn, Wb, (void*)qkv, 1024);
  k_kvred<<<dim3(32, 16), 256, 0, stream>>>(qkv, rope, KV, Ksum);
  k_qkern<<<4096, 256, 0, stream>>>(qkv, rope, KV, Ksum, Yb);
  k_gemm128<false><<<dim3(256, 4), 256, 0, stream>>>(Yb, wob, (void*)out, 512);
}